// Round 2
// baseline (413.554 us; speedup 1.0000x reference)
//
#include <hip/hip_runtime.h>
#include <hip/hip_bf16.h>
#include <stdint.h>

// Conv 3x3 SAME, NHWC fp32 in/out, implicit GEMM via bf16 MFMA.
// M = B*H*W = 100352, N = COUT = 256, K = 9*256 = 2304.
// Round 6: revert to round-4 geometry (128x128 tile, BK=64, 256 threads,
// single-buffer LDS, DMA-overlaps-MFMA schedule -- proven 152 us), replace
// the 8-slot XOR swizzle (4-way bank conflict, 14.4M conflict cycles) with a
// PRE-FRAGMENTED LDS layout: each 1024B slice holds one wave64 MFMA fragment
// in lane order. Compute reads are fully contiguous ds_read_b128 (vaddr =
// lane*16 + offset imm) -> zero conflicts, zero per-read address VALU.
// Fragment content identical to round-4; the permutation lives in the
// per-lane global source addresses of global_load_lds.

#define IMG_B 32
#define IMG_H 56
#define IMG_W 56
#define CIN   256
#define COUT  256
#define KDIM  2304          // 3*3*256
#define M_TOT 100352
#define HW    (IMG_H * IMG_W)
#define PW    58            // padded width
#define PHW   (PW * PW)     // 3364 padded pixels per image
#define BK    64            // k-elems per tile
#define ITERS (KDIM / BK)   // 36
#define PAD_BLOCKS 13456    // IMG_B*PHW*CIN / 8 / 256
#define WT_BLOCKS  (KDIM * COUT / 256)   // 2304

typedef __bf16 bf16_t;
typedef bf16_t bf16x8 __attribute__((ext_vector_type(8)));
typedef float  f32x4  __attribute__((ext_vector_type(4)));
typedef float  f32x16 __attribute__((ext_vector_type(16)));

typedef const __attribute__((address_space(1))) void GV;
typedef __attribute__((address_space(3))) void LV;

__device__ __forceinline__ void async16(const bf16_t* g, bf16_t* l) {
    // LDS dest = wave-uniform(l) + laneid*16; 16B per lane
    __builtin_amdgcn_global_load_lds((GV*)g, (LV*)l, 16, 0, 0);
}

// ---------- fused prep: pad image to bf16 [B][58][58][C] + weights -> Wt[co][k] ----------
__global__ void prep_fused(const float* __restrict__ in, const float* __restrict__ kern,
                           bf16_t* __restrict__ pimg, bf16_t* __restrict__ wt) {
    if (blockIdx.x < PAD_BLOCKS) {
        const size_t e = ((size_t)blockIdx.x * 256 + threadIdx.x) * 8;
        const int pix = (int)(e >> 8);          // padded pixel index
        const int c0  = (int)(e & 255);
        const int b   = pix / PHW;
        const int r   = pix - b * PHW;
        const int py  = r / PW;
        const int px  = r - py * PW;
        bf16x8 v = {};                          // border default: zeros
        if (py >= 1 && py <= IMG_H && px >= 1 && px <= IMG_W) {
            const f32x4* s = (const f32x4*)(in +
                ((((size_t)b * IMG_H + (py - 1)) * IMG_W + (px - 1)) << 8) + c0);
            f32x4 a = s[0], bq = s[1];
            #pragma unroll
            for (int k = 0; k < 4; ++k) v[k] = (bf16_t)a[k];
            #pragma unroll
            for (int k = 0; k < 4; ++k) v[4 + k] = (bf16_t)bq[k];
        }
        *(bf16x8*)(pimg + e) = v;
    } else {
        const int idx = (blockIdx.x - PAD_BLOCKS) * 256 + threadIdx.x;
        const int co  = idx / KDIM;
        const int k   = idx - co * KDIM;
        wt[idx] = (bf16_t)kern[k * COUT + co];  // coalesced bf16 writes
    }
}

// ---------- standalone weight prep (fallback path only) ----------
__global__ void prep_weights(const float* __restrict__ kern, bf16_t* __restrict__ wt) {
    int idx = blockIdx.x * 256 + threadIdx.x;
    int co  = idx / KDIM;
    int k   = idx - co * KDIM;
    wt[idx] = (bf16_t)kern[k * COUT + co];
}

// ---------- main conv: 128x128 tile, BK=64, pre-fragmented conflict-free LDS ----------
// LDS layout per tile (A and B identical): 16 slices of 1024 B.
// Slice s = rg*4 + kk  (rg = tile-row>>5, kk = k-pair index):
//   lane l holds row rg*32 + (l&31), k-elems (kk*2 + (l>>5))*8 .. +8
// Compute read of fragment (rg,kk) = ds_read_b128 at slice*1024 + lane*16
// (fully contiguous per wave64 -> no bank conflicts).
__global__ __launch_bounds__(256)
void conv_mfma_p(const bf16_t* __restrict__ P, const bf16_t* __restrict__ wt,
                 const float* __restrict__ bias, float* __restrict__ out)
{
    __shared__ __align__(1024) bf16_t Al[128 * BK];   // 16 KB
    __shared__ __align__(1024) bf16_t Bl[128 * BK];   // 16 KB

    const int tid  = threadIdx.x;
    const int wave = tid >> 6;
    const int lane = tid & 63;

    // XCD-contiguous tile mapping: blocks on one XCD cover 196 contiguous tiles
    const int bid   = blockIdx.x;
    const int tile  = (bid & 7) * 196 + (bid >> 3);
    const int ntile = tile & 1;
    const int mtile = tile >> 1;

    // ---- staging roles: wave w stages slices (rg=w, kk=0..3) of A and B ----
    const int ln32 = lane & 31;
    const int lh   = lane >> 5;           // k-half within a k-pair
    const int arow = wave * 32 + ln32;    // tile row 0..127
    const int m    = mtile * 128 + arow;
    const int bb   = m / HW;
    const int rem  = m - bb * HW;
    const int yy   = rem / IMG_W;
    const int xx   = rem - yy * IMG_W;
    const bf16_t* asrc = P + (((size_t)bb * PHW + yy * PW + xx) << 8) + lh * 8;
    const bf16_t* bsrc = wt + (size_t)(ntile * 128 + arow) * KDIM + lh * 8;
    bf16_t* alds = &Al[wave * 2048];      // wave-uniform slice base (4 slices)
    bf16_t* blds = &Bl[wave * 2048];

    // ---- compute roles: wave (wm,wn) owns 64x64; 2x2 of 32x32 MFMA tiles ----
    const int wm = wave & 1;
    const int wn = wave >> 1;
    const bf16_t* rA = Al + wm * 4096 + lane * 8;   // + g*2048 + kk*512
    const bf16_t* rB = Bl + wn * 4096 + lane * 8;

    f32x16 acc[2][2] = {};

    // prologue: stage iter 0 (tap 0 => koff 0)
    #pragma unroll
    for (int kk = 0; kk < 4; ++kk) async16(asrc + kk * 16, alds + kk * 512);
    #pragma unroll
    for (int kk = 0; kk < 4; ++kk) async16(bsrc + kk * 16, blds + kk * 512);

    #pragma unroll 1
    for (int it = 0; it < ITERS; ++it) {
        __syncthreads();   // DMA for iter `it` complete in LDS

        // fragment reads: 16 x ds_read_b128, contiguous slices, conflict-free
        bf16x8 af[2][4], bf[2][4];
        #pragma unroll
        for (int kk = 0; kk < 4; ++kk) {
            af[0][kk] = *(const bf16x8*)(rA + kk * 512);
            af[1][kk] = *(const bf16x8*)(rA + 2048 + kk * 512);
            bf[0][kk] = *(const bf16x8*)(rB + kk * 512);
            bf[1][kk] = *(const bf16x8*)(rB + 2048 + kk * 512);
        }

        __syncthreads();   // reads done; LDS free for next iter's DMA

        if (it + 1 < ITERS) {      // issue next DMA BEFORE the MFMA block
            const int itn  = it + 1;
            const int tap  = itn >> 2;
            const int kh   = tap / 3;
            const int kw   = tap - kh * 3;
            const int koff = ((kh * PW + kw) << 8) + ((itn & 3) << 6);
            const int woff = itn * BK;
            #pragma unroll
            for (int kk = 0; kk < 4; ++kk) async16(asrc + koff + kk * 16, alds + kk * 512);
            #pragma unroll
            for (int kk = 0; kk < 4; ++kk) async16(bsrc + woff + kk * 16, blds + kk * 512);
        }

        // MFMA: 16 x 32x32x16 (DMA flight overlaps this)
        #pragma unroll
        for (int kk = 0; kk < 4; ++kk) {
            acc[0][0] = __builtin_amdgcn_mfma_f32_32x32x16_bf16(af[0][kk], bf[0][kk], acc[0][0], 0, 0, 0);
            acc[0][1] = __builtin_amdgcn_mfma_f32_32x32x16_bf16(af[0][kk], bf[1][kk], acc[0][1], 0, 0, 0);
            acc[1][0] = __builtin_amdgcn_mfma_f32_32x32x16_bf16(af[1][kk], bf[0][kk], acc[1][0], 0, 0, 0);
            acc[1][1] = __builtin_amdgcn_mfma_f32_32x32x16_bf16(af[1][kk], bf[1][kk], acc[1][1], 0, 0, 0);
        }
    }

    // ---- epilogue: 32x32 C/D layout col=lane&31, row=(reg&3)+8*(reg>>2)+4*lh ----
    const int ln     = lane & 31;
    const int lhh    = lane >> 5;
    const int mbase  = mtile * 128 + wm * 64;
    const int cobase = ntile * 128 + wn * 64;
    float bv[2];
    bv[0] = bias[cobase + ln];
    bv[1] = bias[cobase + 32 + ln];

    #pragma unroll
    for (int g = 0; g < 2; ++g) {
        #pragma unroll
        for (int reg = 0; reg < 16; ++reg) {
            const int mm = mbase + g * 32 + (reg & 3) + 8 * (reg >> 2) + 4 * lhh;
            float* op = out + (size_t)mm * COUT + cobase + ln;
            op[0]  = acc[g][0][reg] + bv[0];
            op[32] = acc[g][1][reg] + bv[1];
        }
    }
}

// ---------- fallback conv (fp32 staging, round-1 validated) ----------
#define ASTR 40
#define BSTR 40
__global__ __launch_bounds__(256)
void conv_mfma(const float* __restrict__ in, const bf16_t* __restrict__ wt,
               const float* __restrict__ bias, float* __restrict__ out)
{
    __shared__ bf16_t Alf[128 * ASTR];
    __shared__ bf16_t Blf[128 * BSTR];

    const int tid   = threadIdx.x;
    const int ntile = blockIdx.x & 1;
    const int mtile = blockIdx.x >> 1;

    const int arow = tid >> 1;
    const int aseg = tid & 1;
    const int m    = mtile * 128 + arow;
    const int bb   = m / HW;
    const int rem  = m - bb * HW;
    const int yy   = rem / IMG_W;
    const int xx   = rem - yy * IMG_W;

    const bf16_t* wt_row = wt + (size_t)(ntile * 128 + arow) * KDIM + aseg * 16;

    const int wave = tid >> 6;
    const int lane = tid & 63;
    const int wm   = wave & 1;
    const int wn   = wave >> 1;
    const int lrow = lane & 15;
    const int q    = lane >> 4;

    f32x4 acc[4][4] = {};

    #pragma unroll 1
    for (int it = 0; it < 72; ++it) {
        const int tap = it >> 3;
        const int kh  = tap / 3;
        const int kw  = tap - kh * 3;
        const int ci0 = (it & 7) << 5;

        const int iy = yy + kh - 1;
        const int ix = xx + kw - 1;
        const bool valid = ((unsigned)iy < IMG_H) && ((unsigned)ix < IMG_W);

        f32x4 va[4] = {};
        if (valid) {
            const f32x4* src = (const f32x4*)(in +
                ((((size_t)bb * IMG_H + iy) * IMG_W + ix) * CIN + ci0 + aseg * 16));
            va[0] = src[0]; va[1] = src[1]; va[2] = src[2]; va[3] = src[3];
        }
        const uint4 wb0 = *(const uint4*)(wt_row + it * 32);
        const uint4 wb1 = *(const uint4*)(wt_row + it * 32 + 8);

        __syncthreads();

        bf16x8 pa0, pa1;
        #pragma unroll
        for (int e = 0; e < 8; ++e) pa0[e] = (bf16_t)va[e >> 2][e & 3];
        #pragma unroll
        for (int e = 0; e < 8; ++e) pa1[e] = (bf16_t)va[2 + (e >> 2)][e & 3];
        *(bf16x8*)(&Alf[arow * ASTR + aseg * 16])     = pa0;
        *(bf16x8*)(&Alf[arow * ASTR + aseg * 16 + 8]) = pa1;
        *(uint4*)(&Blf[arow * BSTR + aseg * 16])      = wb0;
        *(uint4*)(&Blf[arow * BSTR + aseg * 16 + 8])  = wb1;

        __syncthreads();

        bf16x8 af[4], bf[4];
        #pragma unroll
        for (int i = 0; i < 4; ++i)
            af[i] = *(const bf16x8*)(&Alf[(wm * 64 + i * 16 + lrow) * ASTR + q * 8]);
        #pragma unroll
        for (int j = 0; j < 4; ++j)
            bf[j] = *(const bf16x8*)(&Blf[(wn * 64 + j * 16 + lrow) * BSTR + q * 8]);

        #pragma unroll
        for (int i = 0; i < 4; ++i)
            #pragma unroll
            for (int j = 0; j < 4; ++j)
                acc[i][j] = __builtin_amdgcn_mfma_f32_16x16x32_bf16(af[i], bf[j], acc[i][j], 0, 0, 0);
    }

    const int co_base = ntile * 128 + wn * 64;
    float bv[4];
    #pragma unroll
    for (int j = 0; j < 4; ++j) bv[j] = bias[co_base + j * 16 + lrow];

    const int mrow_base = mtile * 128 + wm * 64;
    #pragma unroll
    for (int i = 0; i < 4; ++i) {
        #pragma unroll
        for (int rr = 0; rr < 4; ++rr) {
            const int mm = mrow_base + i * 16 + q * 4 + rr;
            float* op = out + (size_t)mm * COUT + co_base;
            #pragma unroll
            for (int j = 0; j < 4; ++j)
                op[j * 16 + lrow] = acc[i][j][rr] + bv[j];
        }
    }
}

extern "C" void kernel_launch(void* const* d_in, const int* in_sizes, int n_in,
                              void* d_out, int out_size, void* d_ws, size_t ws_size,
                              hipStream_t stream) {
    const float* inputs = (const float*)d_in[0];
    const float* kernel = (const float*)d_in[1];
    const float* bias   = (const float*)d_in[2];
    float*       outp   = (float*)d_out;

    const size_t p_elems = (size_t)IMG_B * PHW * CIN;               // 27,557,888
    const size_t p_bytes = p_elems * sizeof(bf16_t);                // 55.1 MB
    const size_t w_bytes = (size_t)KDIM * COUT * sizeof(bf16_t);    // 1.18 MB

    if (ws_size >= p_bytes + w_bytes) {
        bf16_t* pimg = (bf16_t*)d_ws;
        bf16_t* wt   = (bf16_t*)((char*)d_ws + p_bytes);
        prep_fused<<<PAD_BLOCKS + WT_BLOCKS, 256, 0, stream>>>(inputs, kernel, pimg, wt);
        conv_mfma_p<<<(M_TOT / 128) * 2, 256, 0, stream>>>(pimg, wt, bias, outp);
    } else {
        bf16_t* wt = (bf16_t*)d_ws;
        prep_weights<<<WT_BLOCKS, 256, 0, stream>>>(kernel, wt);
        conv_mfma<<<(M_TOT / 128) * 2, 256, 0, stream>>>(inputs, wt, bias, outp);
    }
}

// Round 3
// 321.374 us; speedup vs baseline: 1.2868x; 1.2868x over previous
//
#include <hip/hip_runtime.h>
#include <hip/hip_bf16.h>
#include <stdint.h>

// Conv 3x3 SAME, NHWC fp32 in/out, implicit GEMM via bf16 MFMA.
// M = B*H*W = 100352, N = COUT = 256, K = 9*256 = 2304.
// Round 7: round-4 geometry (128x128 tile, BK=64, 256 threads, 128B-row
// staging with u=sl^rl permutation, swizzled b128 reads -- proven 152 us)
// + T3/T4: LDS double-buffer (2x32KB, still 2 blocks/CU), 2-deep prefetch,
// raw s_barrier with counted vmcnt(8) (never drain-0 in steady state),
// + T5 setprio around the MFMA cluster.

#define IMG_B 32
#define IMG_H 56
#define IMG_W 56
#define CIN   256
#define COUT  256
#define KDIM  2304          // 3*3*256
#define M_TOT 100352
#define HW    (IMG_H * IMG_W)
#define PW    58            // padded width
#define PHW   (PW * PW)     // 3364 padded pixels per image
#define BK    64            // k-elems per tile
#define ITERS (KDIM / BK)   // 36
#define TILE_E (128 * BK)   // 8192 elems = 16 KB per buffer
#define PAD_BLOCKS 13456    // IMG_B*PHW*CIN / 8 / 256
#define WT_BLOCKS  (KDIM * COUT / 256)   // 2304

typedef __bf16 bf16_t;
typedef bf16_t bf16x8 __attribute__((ext_vector_type(8)));
typedef float  f32x4  __attribute__((ext_vector_type(4)));
typedef float  f32x16 __attribute__((ext_vector_type(16)));

typedef const __attribute__((address_space(1))) void GV;
typedef __attribute__((address_space(3))) void LV;

__device__ __forceinline__ void async16(const bf16_t* g, bf16_t* l) {
    // LDS dest = wave-uniform(l) + laneid*16; 16B per lane
    __builtin_amdgcn_global_load_lds((GV*)g, (LV*)l, 16, 0, 0);
}

// ---------- fused prep: pad image to bf16 [B][58][58][C] + weights -> Wt[co][k] ----------
__global__ void prep_fused(const float* __restrict__ in, const float* __restrict__ kern,
                           bf16_t* __restrict__ pimg, bf16_t* __restrict__ wt) {
    if (blockIdx.x < PAD_BLOCKS) {
        const size_t e = ((size_t)blockIdx.x * 256 + threadIdx.x) * 8;
        const int pix = (int)(e >> 8);          // padded pixel index
        const int c0  = (int)(e & 255);
        const int b   = pix / PHW;
        const int r   = pix - b * PHW;
        const int py  = r / PW;
        const int px  = r - py * PW;
        bf16x8 v = {};                          // border default: zeros
        if (py >= 1 && py <= IMG_H && px >= 1 && px <= IMG_W) {
            const f32x4* s = (const f32x4*)(in +
                ((((size_t)b * IMG_H + (py - 1)) * IMG_W + (px - 1)) << 8) + c0);
            f32x4 a = s[0], bq = s[1];
            #pragma unroll
            for (int k = 0; k < 4; ++k) v[k] = (bf16_t)a[k];
            #pragma unroll
            for (int k = 0; k < 4; ++k) v[4 + k] = (bf16_t)bq[k];
        }
        *(bf16x8*)(pimg + e) = v;
    } else {
        const int idx = (blockIdx.x - PAD_BLOCKS) * 256 + threadIdx.x;
        const int co  = idx / KDIM;
        const int k   = idx - co * KDIM;
        wt[idx] = (bf16_t)kern[k * COUT + co];  // coalesced bf16 writes
    }
}

// ---------- standalone weight prep (fallback path only) ----------
__global__ void prep_weights(const float* __restrict__ kern, bf16_t* __restrict__ wt) {
    int idx = blockIdx.x * 256 + threadIdx.x;
    int co  = idx / KDIM;
    int k   = idx - co * KDIM;
    wt[idx] = (bf16_t)kern[k * COUT + co];
}

// ---------- main conv: 128x128 tile, BK=64, double-buffered counted-vmcnt pipeline ----------

// stage k-step (t1) into buffer (cb): 8 async16, 128B-contiguous per row,
// lane->(row,seg) permuted by u = sl^rl (conflict-managed read swizzle).
#define STAGE(t1, cb) do { \
    const int tap_  = (t1) >> 2; \
    const int kh_   = tap_ / 3; \
    const int kw_   = tap_ - kh_ * 3; \
    const int koff_ = ((kh_ * PW + kw_) << 8) + (((t1) & 3) << 6); \
    const int woff_ = (t1) * BK; \
    _Pragma("unroll") \
    for (int i_ = 0; i_ < 4; ++i_) { \
        async16(asrc[i_] + koff_, alds[i_] + (cb) * TILE_E); \
        async16(bsrc[i_] + woff_, blds[i_] + (cb) * TILE_E); \
    } \
} while (0)

// One K-step on buffer (cur): wait STAGE(t) landed (STAGE(t+1) stays in
// flight), read fragments, barrier, stage t+2 into the same buffer, MFMA.
#define STEP(t, cur) do { \
    if ((t) + 1 < ITERS) asm volatile("s_waitcnt vmcnt(8)" ::: "memory"); \
    else                 asm volatile("s_waitcnt vmcnt(0)" ::: "memory"); \
    __builtin_amdgcn_s_barrier(); \
    __builtin_amdgcn_sched_barrier(0); \
    bf16x8 af[2][4], bfr[2][4]; \
    _Pragma("unroll") \
    for (int kk = 0; kk < 4; ++kk) { \
        const int slot_ = ((kk * 2 + lh) ^ rx) * 8; \
        af[0][kk]  = *(const bf16x8*)(&Al[cur][(wm * 64 + ln) * BK + slot_]); \
        af[1][kk]  = *(const bf16x8*)(&Al[cur][(wm * 64 + 32 + ln) * BK + slot_]); \
        bfr[0][kk] = *(const bf16x8*)(&Bl[cur][(wn * 64 + ln) * BK + slot_]); \
        bfr[1][kk] = *(const bf16x8*)(&Bl[cur][(wn * 64 + 32 + ln) * BK + slot_]); \
    } \
    asm volatile("s_waitcnt lgkmcnt(0)" ::: "memory"); \
    __builtin_amdgcn_s_barrier(); \
    __builtin_amdgcn_sched_barrier(0); \
    if ((t) + 2 < ITERS) STAGE((t) + 2, cur); \
    __builtin_amdgcn_s_setprio(1); \
    _Pragma("unroll") \
    for (int kk = 0; kk < 4; ++kk) { \
        acc[0][0] = __builtin_amdgcn_mfma_f32_32x32x16_bf16(af[0][kk], bfr[0][kk], acc[0][0], 0, 0, 0); \
        acc[0][1] = __builtin_amdgcn_mfma_f32_32x32x16_bf16(af[0][kk], bfr[1][kk], acc[0][1], 0, 0, 0); \
        acc[1][0] = __builtin_amdgcn_mfma_f32_32x32x16_bf16(af[1][kk], bfr[0][kk], acc[1][0], 0, 0, 0); \
        acc[1][1] = __builtin_amdgcn_mfma_f32_32x32x16_bf16(af[1][kk], bfr[1][kk], acc[1][1], 0, 0, 0); \
    } \
    __builtin_amdgcn_s_setprio(0); \
} while (0)

__global__ __launch_bounds__(256)
void conv_mfma_p(const bf16_t* __restrict__ P, const bf16_t* __restrict__ wt,
                 const float* __restrict__ bias, float* __restrict__ out)
{
    __shared__ bf16_t Al[2][TILE_E];   // 2 x 16 KB
    __shared__ bf16_t Bl[2][TILE_E];   // 2 x 16 KB  (64 KB total -> 2 blocks/CU)

    const int tid  = threadIdx.x;
    const int wave = tid >> 6;
    const int lane = tid & 63;

    // XCD-contiguous tile mapping: blocks on one XCD cover 196 contiguous tiles
    const int bid   = blockIdx.x;
    const int tile  = (bid & 7) * 196 + (bid >> 3);
    const int ntile = tile & 1;
    const int mtile = tile >> 1;

    // ---- staging roles: per DMA issue, 8 rows x 8 segs of 16B per wave ----
    const int rl = lane >> 3;         // row within 8-row group
    const int sl = lane & 7;          // LDS slot within row
    const int u  = sl ^ rl;           // swizzle: slot sl holds source seg u = sl^(row&7)

    const bf16_t* asrc[4];
    const bf16_t* bsrc[4];
    bf16_t* alds[4];
    bf16_t* blds[4];
    #pragma unroll
    for (int i = 0; i < 4; ++i) {
        const int row = wave * 32 + i * 8 + rl;     // tile row 0..127
        const int m   = mtile * 128 + row;
        const int bb  = m / HW;
        const int rem = m - bb * HW;
        const int yy  = rem / IMG_W;
        const int xx  = rem - yy * IMG_W;
        asrc[i] = P + (((size_t)bb * PHW + yy * PW + xx) << 8) + u * 8;
        const int co = ntile * 128 + row;
        bsrc[i] = wt + (size_t)co * KDIM + u * 8;
        alds[i] = &Al[0][(wave * 32 + i * 8) * BK];  // wave-uniform bases (buf 0)
        blds[i] = &Bl[0][(wave * 32 + i * 8) * BK];
    }

    // ---- compute roles: wave (wm,wn) owns 64x64; 2x2 of 32x32 MFMA tiles ----
    const int wm = wave & 1;
    const int wn = wave >> 1;
    const int ln = lane & 31;
    const int lh = lane >> 5;
    const int rx = ln & 7;            // row&7 for swizzled read

    f32x16 acc[2][2] = {};

    // prologue: stage iters 0 and 1 (16 loads in flight)
    STAGE(0, 0);
    STAGE(1, 1);

    #pragma unroll 1
    for (int it2 = 0; it2 < ITERS / 2; ++it2) {
        const int t0 = it2 * 2;
        STEP(t0,     0);
        STEP(t0 + 1, 1);
    }

    // ---- epilogue: 32x32 C/D layout col=lane&31, row=(reg&3)+8*(reg>>2)+4*lh ----
    const int mbase  = mtile * 128 + wm * 64;
    const int cobase = ntile * 128 + wn * 64;
    float bv[2];
    bv[0] = bias[cobase + ln];
    bv[1] = bias[cobase + 32 + ln];

    #pragma unroll
    for (int g = 0; g < 2; ++g) {
        #pragma unroll
        for (int reg = 0; reg < 16; ++reg) {
            const int mm = mbase + g * 32 + (reg & 3) + 8 * (reg >> 2) + 4 * lh;
            float* op = out + (size_t)mm * COUT + cobase + ln;
            op[0]  = acc[g][0][reg] + bv[0];
            op[32] = acc[g][1][reg] + bv[1];
        }
    }
}

// ---------- fallback conv (fp32 staging, round-1 validated) ----------
#define ASTR 40
#define BSTR 40
__global__ __launch_bounds__(256)
void conv_mfma(const float* __restrict__ in, const bf16_t* __restrict__ wt,
               const float* __restrict__ bias, float* __restrict__ out)
{
    __shared__ bf16_t Alf[128 * ASTR];
    __shared__ bf16_t Blf[128 * BSTR];

    const int tid   = threadIdx.x;
    const int ntile = blockIdx.x & 1;
    const int mtile = blockIdx.x >> 1;

    const int arow = tid >> 1;
    const int aseg = tid & 1;
    const int m    = mtile * 128 + arow;
    const int bb   = m / HW;
    const int rem  = m - bb * HW;
    const int yy   = rem / IMG_W;
    const int xx   = rem - yy * IMG_W;

    const bf16_t* wt_row = wt + (size_t)(ntile * 128 + arow) * KDIM + aseg * 16;

    const int wave = tid >> 6;
    const int lane = tid & 63;
    const int wm   = wave & 1;
    const int wn   = wave >> 1;
    const int lrow = lane & 15;
    const int q    = lane >> 4;

    f32x4 acc[4][4] = {};

    #pragma unroll 1
    for (int it = 0; it < 72; ++it) {
        const int tap = it >> 3;
        const int kh  = tap / 3;
        const int kw  = tap - kh * 3;
        const int ci0 = (it & 7) << 5;

        const int iy = yy + kh - 1;
        const int ix = xx + kw - 1;
        const bool valid = ((unsigned)iy < IMG_H) && ((unsigned)ix < IMG_W);

        f32x4 va[4] = {};
        if (valid) {
            const f32x4* src = (const f32x4*)(in +
                ((((size_t)bb * IMG_H + iy) * IMG_W + ix) * CIN + ci0 + aseg * 16));
            va[0] = src[0]; va[1] = src[1]; va[2] = src[2]; va[3] = src[3];
        }
        const uint4 wb0 = *(const uint4*)(wt_row + it * 32);
        const uint4 wb1 = *(const uint4*)(wt_row + it * 32 + 8);

        __syncthreads();

        bf16x8 pa0, pa1;
        #pragma unroll
        for (int e = 0; e < 8; ++e) pa0[e] = (bf16_t)va[e >> 2][e & 3];
        #pragma unroll
        for (int e = 0; e < 8; ++e) pa1[e] = (bf16_t)va[2 + (e >> 2)][e & 3];
        *(bf16x8*)(&Alf[arow * ASTR + aseg * 16])     = pa0;
        *(bf16x8*)(&Alf[arow * ASTR + aseg * 16 + 8]) = pa1;
        *(uint4*)(&Blf[arow * BSTR + aseg * 16])      = wb0;
        *(uint4*)(&Blf[arow * BSTR + aseg * 16 + 8])  = wb1;

        __syncthreads();

        bf16x8 af[4], bf[4];
        #pragma unroll
        for (int i = 0; i < 4; ++i)
            af[i] = *(const bf16x8*)(&Alf[(wm * 64 + i * 16 + lrow) * ASTR + q * 8]);
        #pragma unroll
        for (int j = 0; j < 4; ++j)
            bf[j] = *(const bf16x8*)(&Blf[(wn * 64 + j * 16 + lrow) * BSTR + q * 8]);

        #pragma unroll
        for (int i = 0; i < 4; ++i)
            #pragma unroll
            for (int j = 0; j < 4; ++j)
                acc[i][j] = __builtin_amdgcn_mfma_f32_16x16x32_bf16(af[i], bf[j], acc[i][j], 0, 0, 0);
    }

    const int co_base = ntile * 128 + wn * 64;
    float bv[4];
    #pragma unroll
    for (int j = 0; j < 4; ++j) bv[j] = bias[co_base + j * 16 + lrow];

    const int mrow_base = mtile * 128 + wm * 64;
    #pragma unroll
    for (int i = 0; i < 4; ++i) {
        #pragma unroll
        for (int rr = 0; rr < 4; ++rr) {
            const int mm = mrow_base + i * 16 + q * 4 + rr;
            float* op = out + (size_t)mm * COUT + co_base;
            #pragma unroll
            for (int j = 0; j < 4; ++j)
                op[j * 16 + lrow] = acc[i][j][rr] + bv[j];
        }
    }
}

extern "C" void kernel_launch(void* const* d_in, const int* in_sizes, int n_in,
                              void* d_out, int out_size, void* d_ws, size_t ws_size,
                              hipStream_t stream) {
    const float* inputs = (const float*)d_in[0];
    const float* kernel = (const float*)d_in[1];
    const float* bias   = (const float*)d_in[2];
    float*       outp   = (float*)d_out;

    const size_t p_elems = (size_t)IMG_B * PHW * CIN;               // 27,557,888
    const size_t p_bytes = p_elems * sizeof(bf16_t);                // 55.1 MB
    const size_t w_bytes = (size_t)KDIM * COUT * sizeof(bf16_t);    // 1.18 MB

    if (ws_size >= p_bytes + w_bytes) {
        bf16_t* pimg = (bf16_t*)d_ws;
        bf16_t* wt   = (bf16_t*)((char*)d_ws + p_bytes);
        prep_fused<<<PAD_BLOCKS + WT_BLOCKS, 256, 0, stream>>>(inputs, kernel, pimg, wt);
        conv_mfma_p<<<(M_TOT / 128) * 2, 256, 0, stream>>>(pimg, wt, bias, outp);
    } else {
        bf16_t* wt = (bf16_t*)d_ws;
        prep_weights<<<WT_BLOCKS, 256, 0, stream>>>(kernel, wt);
        conv_mfma<<<(M_TOT / 128) * 2, 256, 0, stream>>>(inputs, wt, bias, outp);
    }
}